// Round 6
// baseline (172.392 us; speedup 1.0000x reference)
//
#include <hip/hip_runtime.h>
#include <hip/hip_bf16.h>

typedef unsigned short u16;
typedef __attribute__((ext_vector_type(8))) short bf16x8;
typedef __attribute__((ext_vector_type(4))) float f32x4;

#define N_MEM_C 65536
#define NNODES_C 50000
#define DDIM 128
#define LDA 136   // 272B rows: breaks power-of-2 bank aliasing
#define BM 128
#define NTHR 512
#define TIL(t) ((t) * 16384)

// bf16 [n][k] weight tiles (128x128 each):
// 0: msg_W1[0:128]^T (vi)   1: msg_W1[256:384]^T (vj)   2: msg_W2^T
// 3: hid_W1[0:128]^T (aggr) 4: hid_W1[128:256]^T (hidden)
// 5: (int_W @ hid_W1[256:384])^T    6: hid_W2^T
__device__ __align__(16) u16 g_WT[7 * 16384];
// f32 gather-add tables
__device__ __align__(16) float g_relW[500 * 128];   // rel_table @ msg_W1[128:256]
__device__ __align__(16) float g_qsumM[64 * 128];   // qh@msg_W1[384:512] + qr@msg_W1[512:640]
__device__ __align__(16) float g_qsumH[64 * 128];   // same for hid_W1

__device__ __forceinline__ u16 f2bf_s(float f) {
  __hip_bfloat16 h = __float2bfloat16(f);
  u16 u; __builtin_memcpy(&u, &h, 2);
  return u;
}
__device__ __forceinline__ unsigned pk2(float a, float b) {
  __hip_bfloat162 h = __float22bfloat162_rn(make_float2(a, b));  // v_cvt_pk_bf16_f32
  unsigned u; __builtin_memcpy(&u, &h, 4);
  return u;
}
__device__ __forceinline__ float fast_tanh(float x) {
  float e = __expf(2.0f * x);
  return 1.0f - 2.0f / (e + 1.0f);   // inf-safe
}

// ---- prep kernels (unchanged from round 5) ----
extern "C" __global__ void prep_wt(const float* __restrict__ msg_W1,
                                   const float* __restrict__ msg_W2,
                                   const float* __restrict__ hid_W1,
                                   const float* __restrict__ hid_W2) {
  int i = blockIdx.x * 256 + threadIdx.x;
  int t = i >> 14, idx = i & 16383;
  int n = idx >> 7, k = idx & 127;
  const float* src; int dst;
  switch (t) {
    case 0:  src = msg_W1;             dst = TIL(0); break;
    case 1:  src = msg_W1 + 256 * 128; dst = TIL(1); break;
    case 2:  src = msg_W2;             dst = TIL(2); break;
    case 3:  src = hid_W1;             dst = TIL(3); break;
    case 4:  src = hid_W1 + 128 * 128; dst = TIL(4); break;
    default: src = hid_W2;             dst = TIL(6); break;
  }
  g_WT[dst + n * 128 + k] = f2bf_s(src[k * 128 + n]);
}

extern "C" __global__ void prep_weff(const float* __restrict__ hid_W1,
                                     const float* __restrict__ int_W) {
  int i = blockIdx.x * 256 + threadIdx.x;
  int n = i & 127, q = i >> 7;
  float s = 0.f;
  for (int p = 0; p < 128; ++p)
    s += int_W[q * 128 + p] * hid_W1[(256 + p) * 128 + n];
  g_WT[TIL(5) + n * 128 + q] = f2bf_s(s);
}

extern "C" __global__ void prep_relW(const float* __restrict__ rel_table,
                                     const float* __restrict__ msg_W1) {
  int i = blockIdx.x * 256 + threadIdx.x;
  if (i >= 500 * 128) return;
  int r = i >> 7, n = i & 127;
  float s = 0.f;
  for (int k = 0; k < 128; ++k)
    s += rel_table[r * 128 + k] * msg_W1[(128 + k) * 128 + n];
  g_relW[i] = s;
}

extern "C" __global__ void prep_qsum(const float* __restrict__ qh,
                                     const float* __restrict__ qr,
                                     const float* __restrict__ msg_W1,
                                     const float* __restrict__ hid_W1) {
  int i = blockIdx.x * 256 + threadIdx.x;
  int g = i >> 7, n = i & 127;
  float sM = 0.f, sH = 0.f;
  for (int k = 0; k < 128; ++k) {
    float h = qh[g * 128 + k], r = qr[g * 128 + k];
    sM += h * msg_W1[(384 + k) * 128 + n] + r * msg_W1[(512 + k) * 128 + n];
    sH += h * hid_W1[(384 + k) * 128 + n] + r * hid_W1[(512 + k) * 128 + n];
  }
  g_qsumM[i] = sM;
  g_qsumH[i] = sH;
}

// ---- staging: gather f32 rows -> bf16 LDS tile (512 threads) ----
// MODE 0: idx from LDS array; MODE 1: idx = base + r; MODE 2: idx from array, scaled
template <int MODE>
__device__ __forceinline__ void stage_rows(u16 (*A)[LDA], const float* __restrict__ src,
                                           const int* idxArr, const float* scArr,
                                           int base, int tid) {
#pragma unroll
  for (int it = 0; it < 2; ++it) {
    int slot = it * NTHR + tid;         // 1024 slots = 128 rows x 8 (16 floats)
    int r = slot >> 3, seg = slot & 7;
    int idx = (MODE == 1) ? (base + r) : idxArr[r];
    float sc = (MODE == 2) ? scArr[r] : 1.0f;
    const float4* p = (const float4*)(src + (size_t)idx * DDIM + seg * 16);
    float4 f0 = p[0], f1 = p[1], f2 = p[2], f3 = p[3];
    if (MODE == 2) {
      f0.x *= sc; f0.y *= sc; f0.z *= sc; f0.w *= sc;
      f1.x *= sc; f1.y *= sc; f1.z *= sc; f1.w *= sc;
      f2.x *= sc; f2.y *= sc; f2.z *= sc; f2.w *= sc;
      f3.x *= sc; f3.y *= sc; f3.z *= sc; f3.w *= sc;
    }
    uint4* q = (uint4*)&A[r][seg * 16];
    q[0] = make_uint4(pk2(f0.x, f0.y), pk2(f0.z, f0.w), pk2(f1.x, f1.y), pk2(f1.z, f1.w));
    q[1] = make_uint4(pk2(f2.x, f2.y), pk2(f2.z, f2.w), pk2(f3.x, f3.y), pk2(f3.z, f3.w));
  }
}

// A(128x128 LDS) @ WT(128x128 bf16 [n][k], read from global/L2) -> acc[4][2]
// wave sub-tile: rows wr*64..+64, cols wc*32..+32
__device__ __forceinline__ void gemm128g(const u16 (*A)[LDA], const u16* __restrict__ WT,
                                         f32x4 (&acc)[4][2], int wr, int wc, int l16, int l4) {
  const u16* wb = WT + (wc * 32 + l16) * 128 + l4 * 8;
#pragma unroll
  for (int ks = 0; ks < 4; ++ks) {
    bf16x8 av[4], bv[2];
#pragma unroll
    for (int nr = 0; nr < 2; ++nr)
      bv[nr] = *(const bf16x8*)(wb + nr * 16 * 128 + ks * 32);
#pragma unroll
    for (int mr = 0; mr < 4; ++mr)
      av[mr] = *(const bf16x8*)&A[wr * 64 + mr * 16 + l16][ks * 32 + l4 * 8];
#pragma unroll
    for (int mr = 0; mr < 4; ++mr)
#pragma unroll
      for (int nr = 0; nr < 2; ++nr)
        acc[mr][nr] = __builtin_amdgcn_mfma_f32_16x16x32_bf16(av[mr], bv[nr], acc[mr][nr], 0, 0, 0);
  }
}

extern "C" __global__ __launch_bounds__(NTHR, 4) void fused_flow(
    const float* __restrict__ hidden, const int* __restrict__ seen_edges,
    const int* __restrict__ memorized, const float* __restrict__ node_att,
    const float* __restrict__ hidden_uncon,
    const float* __restrict__ msg_b1, const float* __restrict__ msg_b2,
    const float* __restrict__ hid_b1, const float* __restrict__ hid_b2,
    float* __restrict__ out) {
  __shared__ u16 sA[BM][LDA];
  __shared__ int sEg[4][BM];
  __shared__ int sRel[4][BM];
  __shared__ int sVi[4][BM];
  __shared__ int sMeg[BM];
  __shared__ int sMvm[BM];
  __shared__ float sNA[BM];

  const int tid = threadIdx.x;
  const int lane = tid & 63, wid = tid >> 6;
  const int wr = wid >> 2, wc = wid & 3;     // 2 x 4 wave grid
  const int l16 = lane & 15, l4 = lane >> 4;
  const int j0 = blockIdx.x * BM;

  float mb1v[2], mb2v[2], hb1v[2], hb2v[2];
#pragma unroll
  for (int nr = 0; nr < 2; ++nr) {
    int col = wc * 32 + nr * 16 + l16;
    mb1v[nr] = msg_b1[col]; mb2v[nr] = msg_b2[col];
    hb1v[nr] = hid_b1[col]; hb2v[nr] = hid_b2[col];
  }

  // ---- upfront: all edge-tile indices + update-phase gathers + phase-V stage ----
  {
    int t = tid >> 7, r = tid & 127;          // 512 threads -> all 4 tiles x 128 rows
    int e = j0 + r + t * N_MEM_C;
    const int4* se = (const int4*)seen_edges + (size_t)e * 2;
    int4 lo = se[0], hi = se[1];
    sEg[t][r] = min(max(lo.x, 0), 63);
    sRel[t][r] = min(max(lo.w, 0), 499);
    sVi[t][r] = min(max(hi.z, 0), N_MEM_C - 1);
  }
  if (tid < BM) {
    int2 mn = ((const int2*)memorized)[j0 + tid];
    int eg = min(max(mn.x, 0), 63);
    int vm = min(max(mn.y, 0), NNODES_C - 1);
    sMeg[tid] = eg; sMvm[tid] = vm;
    sNA[tid] = node_att[(size_t)eg * NNODES_C + vm];
  }
  stage_rows<1>(sA, hidden, nullptr, nullptr, j0, tid);
  __syncthreads();

  const f32x4 zero4 = {0.f, 0.f, 0.f, 0.f};
  f32x4 acc_vj[4][2], aggr[4][2];
#pragma unroll
  for (int a = 0; a < 4; ++a)
#pragma unroll
    for (int b = 0; b < 2; ++b) { acc_vj[a][b] = zero4; aggr[a][b] = zero4; }
  gemm128g(sA, g_WT + TIL(1), acc_vj, wr, wc, l16, l4);

  // ---- edge-message phase: 4 tiles of 128 edges ----
#pragma unroll 1
  for (int t = 0; t < 4; ++t) {
    __syncthreads();                    // prev readers of sA done
    stage_rows<0>(sA, hidden, sVi[t], nullptr, 0, tid);
    __syncthreads();

    f32x4 acc[4][2];
#pragma unroll
    for (int a = 0; a < 4; ++a)
#pragma unroll
      for (int b = 0; b < 2; ++b) acc[a][b] = acc_vj[a][b];
    gemm128g(sA, g_WT + TIL(0), acc, wr, wc, l16, l4);

    // gather-add: rel + query contributions (f32 tables, L2)
#pragma unroll
    for (int mr = 0; mr < 4; ++mr)
#pragma unroll
      for (int i = 0; i < 4; ++i) {
        int r = wr * 64 + mr * 16 + l4 * 4 + i;
        const float* pr = g_relW + sRel[t][r] * 128;
        const float* pq = g_qsumM + sEg[t][r] * 128;
#pragma unroll
        for (int nr = 0; nr < 2; ++nr) {
          int c = wc * 32 + nr * 16 + l16;
          acc[mr][nr][i] += pr[c] + pq[c];
        }
      }
    __syncthreads();                    // all waves done reading sA

    // epilogue 1: h = leaky_relu(acc + b1) -> sA
#pragma unroll
    for (int mr = 0; mr < 4; ++mr)
#pragma unroll
      for (int nr = 0; nr < 2; ++nr)
#pragma unroll
        for (int i = 0; i < 4; ++i) {
          float v = acc[mr][nr][i] + mb1v[nr];
          v = (v >= 0.f) ? v : 0.2f * v;
          sA[wr * 64 + mr * 16 + l4 * 4 + i][wc * 32 + nr * 16 + l16] = f2bf_s(v);
        }
    __syncthreads();

    f32x4 acc2[4][2];
#pragma unroll
    for (int a = 0; a < 4; ++a)
#pragma unroll
      for (int b = 0; b < 2; ++b) acc2[a][b] = zero4;
    gemm128g(sA, g_WT + TIL(2), acc2, wr, wc, l16, l4);
#pragma unroll
    for (int mr = 0; mr < 4; ++mr)
#pragma unroll
      for (int nr = 0; nr < 2; ++nr)
#pragma unroll
        for (int i = 0; i < 4; ++i)
          aggr[mr][nr][i] += fast_tanh(acc2[mr][nr][i] + mb2v[nr]);
  }

  // ---- update phase ----
  __syncthreads();
  // chunk 0: message_aggr = 0.5 * aggr -> sA
#pragma unroll
  for (int mr = 0; mr < 4; ++mr)
#pragma unroll
    for (int nr = 0; nr < 2; ++nr)
#pragma unroll
      for (int i = 0; i < 4; ++i)
        sA[wr * 64 + mr * 16 + l4 * 4 + i][wc * 32 + nr * 16 + l16] =
            f2bf_s(0.5f * aggr[mr][nr][i]);
  __syncthreads();
  f32x4 accU[4][2];
#pragma unroll
  for (int a = 0; a < 4; ++a)
#pragma unroll
    for (int b = 0; b < 2; ++b) accU[a][b] = zero4;
  gemm128g(sA, g_WT + TIL(3), accU, wr, wc, l16, l4);
  __syncthreads();

  // chunk 1: hidden[m]
  stage_rows<1>(sA, hidden, nullptr, nullptr, j0, tid);
  __syncthreads();
  gemm128g(sA, g_WT + TIL(4), accU, wr, wc, l16, l4);
  __syncthreads();

  // chunk 2: na * hidden_uncon[v_m] @ Weff
  stage_rows<2>(sA, hidden_uncon, sMvm, sNA, 0, tid);
  __syncthreads();
  gemm128g(sA, g_WT + TIL(5), accU, wr, wc, l16, l4);

  // gather-add: query chunks for the update MLP
#pragma unroll
  for (int mr = 0; mr < 4; ++mr)
#pragma unroll
    for (int i = 0; i < 4; ++i) {
      int r = wr * 64 + mr * 16 + l4 * 4 + i;
      const float* pq = g_qsumH + sMeg[r] * 128;
#pragma unroll
      for (int nr = 0; nr < 2; ++nr)
        accU[mr][nr][i] += pq[wc * 32 + nr * 16 + l16];
    }
  __syncthreads();

  // epilogue 2: h -> sA, GEMM with hid_W2, out = hidden + tanh(.. + b2)
#pragma unroll
  for (int mr = 0; mr < 4; ++mr)
#pragma unroll
    for (int nr = 0; nr < 2; ++nr)
#pragma unroll
      for (int i = 0; i < 4; ++i) {
        float v = accU[mr][nr][i] + hb1v[nr];
        v = (v >= 0.f) ? v : 0.2f * v;
        sA[wr * 64 + mr * 16 + l4 * 4 + i][wc * 32 + nr * 16 + l16] = f2bf_s(v);
      }
  __syncthreads();

  f32x4 acc2[4][2];
#pragma unroll
  for (int a = 0; a < 4; ++a)
#pragma unroll
    for (int b = 0; b < 2; ++b) acc2[a][b] = zero4;
  gemm128g(sA, g_WT + TIL(6), acc2, wr, wc, l16, l4);

#pragma unroll
  for (int mr = 0; mr < 4; ++mr)
#pragma unroll
    for (int nr = 0; nr < 2; ++nr)
#pragma unroll
      for (int i = 0; i < 4; ++i) {
        int row = j0 + wr * 64 + mr * 16 + l4 * 4 + i;
        int col = wc * 32 + nr * 16 + l16;
        size_t o = (size_t)row * DDIM + col;
        out[o] = hidden[o] + fast_tanh(acc2[mr][nr][i] + hb2v[nr]);
      }
}

extern "C" void kernel_launch(void* const* d_in, const int* in_sizes, int n_in,
                              void* d_out, int out_size, void* d_ws, size_t ws_size,
                              hipStream_t stream) {
  (void)in_sizes; (void)n_in; (void)out_size; (void)d_ws; (void)ws_size;
  const float* hidden       = (const float*)d_in[0];
  const int*   seen_edges   = (const int*)d_in[1];
  const int*   memorized    = (const int*)d_in[2];
  const float* node_att     = (const float*)d_in[3];
  const float* hidden_uncon = (const float*)d_in[4];
  const float* qh           = (const float*)d_in[5];
  const float* qr           = (const float*)d_in[6];
  const float* rel_table    = (const float*)d_in[7];
  const float* msg_W1       = (const float*)d_in[8];
  const float* msg_b1       = (const float*)d_in[9];
  const float* msg_W2       = (const float*)d_in[10];
  const float* msg_b2       = (const float*)d_in[11];
  const float* hid_W1       = (const float*)d_in[12];
  const float* hid_b1       = (const float*)d_in[13];
  const float* hid_W2       = (const float*)d_in[14];
  const float* hid_b2       = (const float*)d_in[15];
  const float* int_W        = (const float*)d_in[16];

  prep_wt<<<dim3(6 * 16384 / 256), dim3(256), 0, stream>>>(msg_W1, msg_W2, hid_W1, hid_W2);
  prep_weff<<<dim3(64), dim3(256), 0, stream>>>(hid_W1, int_W);
  prep_relW<<<dim3(250), dim3(256), 0, stream>>>(rel_table, msg_W1);
  prep_qsum<<<dim3(32), dim3(256), 0, stream>>>(qh, qr, msg_W1, hid_W1);
  fused_flow<<<dim3(N_MEM_C / BM), dim3(NTHR), 0, stream>>>(
      hidden, seen_edges, memorized, node_att, hidden_uncon,
      msg_b1, msg_b2, hid_b1, hid_b2, (float*)d_out);
}